// Round 10
// baseline (209.576 us; speedup 1.0000x reference)
//
#include <hip/hip_runtime.h>
#include <stdint.h>

#define DEV __device__ __forceinline__

typedef unsigned short u16;
typedef unsigned int u32;
typedef short bh8 __attribute__((ext_vector_type(8)));
typedef float f32x4 __attribute__((ext_vector_type(4)));

// ---------- bf16 helpers ----------
DEV float bf2f(u16 v){ return __uint_as_float(((u32)v)<<16); }
DEV u16 f2bf(float f){
    u32 x = __float_as_uint(f);
    x += 0x7fffu + ((x>>16)&1u);
    return (u16)(x>>16);
}
DEV void cvt8(int4 r, float* f){
    u32 a=(u32)r.x, b=(u32)r.y, c=(u32)r.z, d=(u32)r.w;
    f[0]=__uint_as_float(a<<16); f[1]=__uint_as_float(a&0xffff0000u);
    f[2]=__uint_as_float(b<<16); f[3]=__uint_as_float(b&0xffff0000u);
    f[4]=__uint_as_float(c<<16); f[5]=__uint_as_float(c&0xffff0000u);
    f[6]=__uint_as_float(d<<16); f[7]=__uint_as_float(d&0xffff0000u);
}
DEV int2 pk4(float a, float b, float c, float d){
    int2 r;
    r.x = (int)((u32)f2bf(a) | ((u32)f2bf(b)<<16));
    r.y = (int)((u32)f2bf(c) | ((u32)f2bf(d)<<16));
    return r;
}
DEV bh8 ld_frag(const u16* p){
    int4 v = *(const int4*)p;
    union{ int4 i; bh8 h; } u; u.i = v; return u.h;
}
#define MFMA __builtin_amdgcn_mfma_f32_16x16x32_bf16

// Problem constants: BSZ=1, S=256, C=128, H=4, D=32, F=64.
// I/O dtype: f32 (R7: bf16-read -> NaN; R8/R9: f32 in/out verified). bf16 internal.

// Param block layout (elements, bf16) inside workspace (R6/R9-verified):
#define P_LNW 0
#define P_LNB 128
#define P_QW  256
#define P_QB  16640
#define P_KW  16768
#define P_KB  33152
#define P_VW  33280
#define P_VB  49664
#define P_QFW 49792
#define P_QFB 50816
#define P_KFW 50848
#define P_KFB 51872
#define P_GW  51904
#define P_GB  68288
#define P_OW  68416
#define P_OB  84800
#define P_TOT 84928
// combined feature-map weights (appended):
#define P_CQW 84928    // [h][j][c] 4*32*128
#define P_CQB 101312   // [h][j]    4*32
#define P_CKW 101440
#define P_CKB 117824

#define NCONV 332      // blocks for the convert part (332*256 >= P_TOT)

// ---------------- params: f32 -> bf16 block + combined q/k feature weights ----------------
__global__ void prep_params(
    const float* p0, const float* p1, const float* p2, const float* p3,
    const float* p4, const float* p5, const float* p6, const float* p7,
    const float* p8, const float* p9, const float* p10, const float* p11,
    const float* p12, const float* p13, const float* p14, const float* p15,
    u16* __restrict__ dst){
    int b = blockIdx.x, tid = threadIdx.x;
    if(b < NCONV){
        int idx = b*256 + tid;
        if(idx >= P_TOT) return;
        const int offs[17] = {P_LNW,P_LNB,P_QW,P_QB,P_KW,P_KB,P_VW,P_VB,
                              P_QFW,P_QFB,P_KFW,P_KFB,P_GW,P_GB,P_OW,P_OB,P_TOT};
        const float* ptrs[16] = {p0,p1,p2,p3,p4,p5,p6,p7,p8,p9,p10,p11,p12,p13,p14,p15};
        int tsel = 0;
        #pragma unroll
        for(int i=1;i<16;++i) if(idx >= offs[i]) tsel = i;
        dst[idx] = f2bf(ptrs[tsel][idx - offs[tsel]]);
    } else if(b < NCONV + 128){
        // combined weights: Wc[h][j][c] = sum_d F[j][d] * W[h*32+d][c]
        int idx = (b - NCONV)*256 + tid;            // [0, 32768)
        int sel = idx >> 14;                        // 0=q, 1=k
        int rem = idx & 16383;
        int h = rem >> 12, j = (rem >> 7) & 31, c = rem & 127;
        const float* FWp = sel ? p10 : p8;
        const float* Wp  = sel ? p4  : p2;
        float s = 0.f;
        #pragma unroll
        for(int d=0; d<32; ++d)
            s += FWp[j*32+d] * Wp[(h*32+d)*128 + c];
        dst[(sel ? P_CKW : P_CQW) + h*4096 + j*128 + c] = f2bf(s);
    } else {
        // combined biases: bc[h][j] = sum_d F[j][d]*b[h*32+d] + fb[j]
        int t = tid;
        int sel = t >> 7, h = (t >> 5) & 3, j = t & 31;
        const float* FWp = sel ? p10 : p8;
        const float* FBp = sel ? p11 : p9;
        const float* Bp  = sel ? p5  : p3;
        float s = FBp[j];
        #pragma unroll
        for(int d=0; d<32; ++d)
            s += FWp[j*32+d] * Bp[h*32+d];
        dst[(sel ? P_CKB : P_CQB) + h*32 + j] = f2bf(s);
    }
}

// ---------------- LayerNorm: one wave per token (f32 in, bf16 out) ----------------
__global__ void ln_kernel(const float* __restrict__ zv, const u16* __restrict__ pb,
                          u16* __restrict__ zn){
    int t = blockIdx.x*4 + (threadIdx.x>>6);
    int lane = threadIdx.x & 63;
    float2 v = ((const float2*)zv)[(size_t)t*64 + lane];
    float x0 = v.x, x1 = v.y;
    float s = x0 + x1, s2 = x0*x0 + x1*x1;
    #pragma unroll
    for(int o=1;o<64;o<<=1){ s += __shfl_xor(s,o,64); s2 += __shfl_xor(s2,o,64); }
    float mean = s*(1.f/128.f);
    float var  = s2*(1.f/128.f) - mean*mean;
    float rs = rsqrtf(var + 1e-5f);
    int c0 = 2*lane;
    float w0 = bf2f(pb[P_LNW+c0]), w1 = bf2f(pb[P_LNW+c0+1]);
    float b0 = bf2f(pb[P_LNB+c0]), b1 = bf2f(pb[P_LNB+c0+1]);
    float o0 = (x0-mean)*rs*w0 + b0;
    float o1 = (x1-mean)*rs*w1 + b1;
    u32 po = (u32)f2bf(o0) | ((u32)f2bf(o1)<<16);
    *(u32*)(zn + (size_t)t*128 + c0) = po;
}

// ---------------- mega kernel: one block per (row, head) ----------------
// XCD swizzle: row = g&255, h = g>>8 -> a row's 4 head-blocks share blockIdx%8 (same XCD L2).
// LDS (bytes), time-multiplexed:
//   kfT  [64][264] u16 @ 0      (33792)  kf^T [f][n]      live P1w -> P2r
//   vT   [32][264] u16 @ 33792  (16896)  v^T [d][n]       live P1w -> P2r
//   qf   [256][72] u16 @ 0      (36864)  [n][f]           live P3w -> P4r (aliases kfT+vT head)
//   kvT  [33][72]  u16 @ 36864  (4752)   kv^T; row32=ksum live P2w -> P4r (inside dead vT tail)
// mask lives in registers (4x int4). 3 syncthreads total.
#define ST_N 264
#define ST_F 72
#define SM_VT   33792
#define SM_KVT  36864
#define SM_TOT  50688

__global__ __launch_bounds__(256,3)
void mega_kernel(const u16* __restrict__ zn, const int* __restrict__ mask,
                 const u16* __restrict__ pb, u16* __restrict__ attn){
    __shared__ __align__(16) char smem[SM_TOT];
    u16* kfT = (u16*)smem;
    u16* vT  = (u16*)(smem + SM_VT);
    u16* qf  = (u16*)smem;
    u16* kvT = (u16*)(smem + SM_KVT);

    int g = blockIdx.x, row = g & 255, h = g >> 8;
    int tid = threadIdx.x, lane = tid & 63, wv = tid >> 6;
    int lm = lane & 15, quad = lane >> 4;

    // mask -> registers (coalesced int4; row slice is L2-hot)
    float mkf[4][4];
    {
        const int4* mp = (const int4*)(mask + row*256);
        #pragma unroll
        for(int mt=0; mt<4; ++mt){
            int4 m4 = mp[wv*16 + mt*4 + quad];
            mkf[mt][0]=(float)m4.x; mkf[mt][1]=(float)m4.y;
            mkf[mt][2]=(float)m4.z; mkf[mt][3]=(float)m4.w;
        }
    }

    // zn A-frags: loaded once, reused by all GEMM phases
    bh8 a[4][4];
    {
        const u16* Ab = zn + ((size_t)row*256 + wv*64 + lm)*128 + quad*8;
        #pragma unroll
        for(int mt=0; mt<4; ++mt)
            #pragma unroll
            for(int ks=0; ks<4; ++ks)
                a[mt][ks] = ld_frag(Ab + (size_t)mt*16*128 + ks*32);
    }
    bh8 onesf;
    { union{int4 i; bh8 h;} u; u.i.x=u.i.y=u.i.z=u.i.w=0x3F803F80; onesf = u.h; }

    f32x4 gacc[4][2];
    // ---- phase 1 (merged): B = [ck0 ck1 | v0 v1 | g0 g1], shared A ----
    {
        f32x4 acc[4][6];
        #pragma unroll
        for(int mt=0;mt<4;++mt)
            #pragma unroll
            for(int j=0;j<6;++j) acc[mt][j] = (f32x4){0,0,0,0};
        #pragma unroll
        for(int ks=0; ks<4; ++ks){
            bh8 b[6];
            b[0] = ld_frag(pb + P_CKW + h*4096 + lm*128            + ks*32 + quad*8);
            b[1] = ld_frag(pb + P_CKW + h*4096 + (16+lm)*128       + ks*32 + quad*8);
            b[2] = ld_frag(pb + P_VW + (size_t)(h*32 + lm)*128     + ks*32 + quad*8);
            b[3] = ld_frag(pb + P_VW + (size_t)(h*32 + 16+lm)*128  + ks*32 + quad*8);
            b[4] = ld_frag(pb + P_GW + (size_t)(h*32 + lm)*128     + ks*32 + quad*8);
            b[5] = ld_frag(pb + P_GW + (size_t)(h*32 + 16+lm)*128  + ks*32 + quad*8);
            #pragma unroll
            for(int mt=0; mt<4; ++mt)
                #pragma unroll
                for(int j=0;j<6;++j)
                    acc[mt][j] = MFMA(a[mt][ks], b[j], acc[mt][j], 0,0,0);
        }
        float bk0 = bf2f(pb[P_CKB + h*32 + lm]);
        float bk1 = bf2f(pb[P_CKB + h*32 + 16 + lm]);
        float bv0 = bf2f(pb[P_VB + h*32 + lm]);
        float bv1 = bf2f(pb[P_VB + h*32 + 16 + lm]);
        float bg0 = bf2f(pb[P_GB + h*32 + lm]);
        float bg1 = bf2f(pb[P_GB + h*32 + 16 + lm]);
        #pragma unroll
        for(int mt=0; mt<4; ++mt){
            int n0 = wv*64 + mt*16 + quad*4;
            float ep0[4], em0[4], ep1[4], em1[4], v0[4], v1[4];
            #pragma unroll
            for(int r=0; r<4; ++r){
                float mk = mkf[mt][r];
                float m0 = fminf(8.f, fmaxf(-8.f, acc[mt][0][r] + bk0));
                float m1 = fminf(8.f, fmaxf(-8.f, acc[mt][1][r] + bk1));
                ep0[r] = __expf( m0)*mk;  em0[r] = __expf(-m0)*mk;
                ep1[r] = __expf( m1)*mk;  em1[r] = __expf(-m1)*mk;
                v0[r] = (acc[mt][2][r] + bv0)*mk;
                v1[r] = (acc[mt][3][r] + bv1)*mk;
                gacc[mt][0][r] = 1.f/(1.f + __expf(-(acc[mt][4][r] + bg0)));
                gacc[mt][1][r] = 1.f/(1.f + __expf(-(acc[mt][5][r] + bg1)));
            }
            *(int2*)(kfT + (size_t)(lm   )*ST_N + n0) = pk4(ep0[0],ep0[1],ep0[2],ep0[3]);
            *(int2*)(kfT + (size_t)(lm+32)*ST_N + n0) = pk4(em0[0],em0[1],em0[2],em0[3]);
            *(int2*)(kfT + (size_t)(lm+16)*ST_N + n0) = pk4(ep1[0],ep1[1],ep1[2],ep1[3]);
            *(int2*)(kfT + (size_t)(lm+48)*ST_N + n0) = pk4(em1[0],em1[1],em1[2],em1[3]);
            *(int2*)(vT  + (size_t)(lm   )*ST_N + n0) = pk4(v0[0],v0[1],v0[2],v0[3]);
            *(int2*)(vT  + (size_t)(16+lm)*ST_N + n0) = pk4(v1[0],v1[1],v1[2],v1[3]);
        }
    }
    __syncthreads();
    // ---- phase 2: kvT[d][f] = sum_n kfT[f][n]*vT[d][n]; ksum via ones-frag ----
    f32x4 acc0=(f32x4){0,0,0,0}, acc1=(f32x4){0,0,0,0}, acc2=(f32x4){0,0,0,0};
    {
        #pragma unroll
        for(int ks=0; ks<8; ++ks){
            bh8 aa = ld_frag(kfT + (size_t)(wv*16+lm)*ST_N + ks*32 + quad*8);
            bh8 b0 = ld_frag(vT + (size_t)lm*ST_N      + ks*32 + quad*8);
            bh8 b1 = ld_frag(vT + (size_t)(16+lm)*ST_N + ks*32 + quad*8);
            acc0 = MFMA(aa, b0, acc0, 0,0,0);
            acc1 = MFMA(aa, b1, acc1, 0,0,0);
            acc2 = MFMA(aa, onesf, acc2, 0,0,0);
        }
    }
    __syncthreads();   // all P2 reads done; kfT/vT now dead
    // ---- kvT write (into dead vT tail) + phase 3 qf compute/write (into dead kfT) ----
    {
        int f0 = wv*16 + quad*4;
        *(int2*)(kvT + (size_t)(lm   )*ST_F + f0) = pk4(acc0[0],acc0[1],acc0[2],acc0[3]);
        *(int2*)(kvT + (size_t)(16+lm)*ST_F + f0) = pk4(acc1[0],acc1[1],acc1[2],acc1[3]);
        if(lm==0)
            *(int2*)(kvT + (size_t)32*ST_F + f0) = pk4(acc2[0],acc2[1],acc2[2],acc2[3]);
    }
    {
        f32x4 acc[4][2];
        #pragma unroll
        for(int mt=0;mt<4;++mt){ acc[mt][0]=(f32x4){0,0,0,0}; acc[mt][1]=(f32x4){0,0,0,0}; }
        #pragma unroll
        for(int ks=0; ks<4; ++ks){
            bh8 b0 = ld_frag(pb + P_CQW + h*4096 + lm*128      + ks*32 + quad*8);
            bh8 b1 = ld_frag(pb + P_CQW + h*4096 + (16+lm)*128 + ks*32 + quad*8);
            #pragma unroll
            for(int mt=0; mt<4; ++mt){
                acc[mt][0] = MFMA(a[mt][ks], b0, acc[mt][0], 0,0,0);
                acc[mt][1] = MFMA(a[mt][ks], b1, acc[mt][1], 0,0,0);
            }
        }
        float bb0 = bf2f(pb[P_CQB + h*32 + lm]);
        float bb1 = bf2f(pb[P_CQB + h*32 + 16 + lm]);
        #pragma unroll
        for(int mt=0; mt<4; ++mt)
            #pragma unroll
            for(int r=0; r<4; ++r){
                int n = wv*64 + mt*16 + quad*4 + r;
                float m0 = fminf(8.f, fmaxf(-8.f, acc[mt][0][r] + bb0));
                float m1 = fminf(8.f, fmaxf(-8.f, acc[mt][1][r] + bb1));
                qf[n*ST_F + lm     ] = f2bf(__expf( m0));
                qf[n*ST_F + lm + 32] = f2bf(__expf(-m0));
                qf[n*ST_F + lm + 16] = f2bf(__expf( m1));
                qf[n*ST_F + lm + 48] = f2bf(__expf(-m1));
            }
    }
    __syncthreads();
    // ---- phase 4: out = (qf·kvT^T)/den * gate ----
    {
        f32x4 acc[4][3];
        #pragma unroll
        for(int mt=0;mt<4;++mt)
            #pragma unroll
            for(int nt=0;nt<3;++nt) acc[mt][nt]=(f32x4){0,0,0,0};
        #pragma unroll
        for(int ks=0; ks<2; ++ks){
            bh8 b0 = ld_frag(kvT + (size_t)lm*ST_F      + ks*32 + quad*8);
            bh8 b1 = ld_frag(kvT + (size_t)(16+lm)*ST_F + ks*32 + quad*8);
            bh8 b2 = ld_frag(kvT + (size_t)32*ST_F      + ks*32 + quad*8); // ksum, broadcast
            #pragma unroll
            for(int mt=0; mt<4; ++mt){
                bh8 aa = ld_frag(qf + (size_t)(wv*64+mt*16+lm)*ST_F + ks*32 + quad*8);
                acc[mt][0] = MFMA(aa, b0, acc[mt][0], 0,0,0);
                acc[mt][1] = MFMA(aa, b1, acc[mt][1], 0,0,0);
                acc[mt][2] = MFMA(aa, b2, acc[mt][2], 0,0,0);
            }
        }
        #pragma unroll
        for(int mt=0; mt<4; ++mt)
            #pragma unroll
            for(int r=0; r<4; ++r){
                int n = wv*64 + mt*16 + quad*4 + r;
                float rcp = 1.f / fmaxf(acc[mt][2][r], 1e-6f);
                u16* op = attn + ((size_t)row*256 + n)*128 + h*32;
                op[lm]    = f2bf(acc[mt][0][r]*rcp*gacc[mt][0][r]);
                op[16+lm] = f2bf(acc[mt][1][r]*rcp*gacc[mt][1][r]);
            }
    }
}

// ---------------- MFMA o-proj: attn(bf16) -> out(f32), x mask ----------------
#define LDS_P 136
__global__ __launch_bounds__(256,3)
void oproj_kernel(const u16* __restrict__ attn, const u16* __restrict__ pb,
                  const int* __restrict__ mask, float* __restrict__ out){
    __shared__ u16 st[128*LDS_P];
    int tid = threadIdx.x;
    int lane = tid&63, wv = tid>>6;
    int mhalf = (wv>>1)*64, nhalf = (wv&1)*64;
    int lm = lane&15, quad = lane>>4;
    int m0 = blockIdx.x*128;

    f32x4 acc[4][4];
    #pragma unroll
    for(int mt=0;mt<4;++mt)
        #pragma unroll
        for(int nt=0;nt<4;++nt)
            acc[mt][nt] = (f32x4){0.f,0.f,0.f,0.f};

    const u16* Abase = attn + (size_t)(m0 + mhalf + lm)*128 + quad*8;
    const u16* W = pb + P_OW;
    #pragma unroll
    for(int ks=0; ks<4; ++ks){
        bh8 a[4], b[4];
        #pragma unroll
        for(int mt=0; mt<4; ++mt)
            a[mt] = ld_frag(Abase + (size_t)mt*16*128 + ks*32);
        #pragma unroll
        for(int nt=0; nt<4; ++nt)
            b[nt] = ld_frag(W + (size_t)(nhalf + nt*16 + lm)*128 + ks*32 + quad*8);
        #pragma unroll
        for(int mt=0; mt<4; ++mt)
            #pragma unroll
            for(int nt=0; nt<4; ++nt)
                acc[mt][nt] = MFMA(a[mt], b[nt], acc[mt][nt], 0, 0, 0);
    }
    float bv[4];
    #pragma unroll
    for(int nt=0; nt<4; ++nt) bv[nt] = bf2f(pb[P_OB + nhalf + nt*16 + lm]);
    #pragma unroll
    for(int mt=0; mt<4; ++mt){
        int mrow = m0 + mhalf + mt*16 + quad*4;
        float mk[4];
        #pragma unroll
        for(int r=0;r<4;++r) mk[r] = (float)mask[mrow+r];
        #pragma unroll
        for(int nt=0; nt<4; ++nt)
            #pragma unroll
            for(int r=0; r<4; ++r){
                float x = (acc[mt][nt][r] + bv[nt]) * mk[r];
                st[(mhalf + mt*16 + quad*4 + r)*LDS_P + nhalf + nt*16 + lm] = f2bf(x);
            }
    }
    __syncthreads();
    {
        int row = tid>>1, half = tid&1;
        const u16* src = st + row*LDS_P + half*64;
        float* dst = out + (size_t)(m0 + row)*128 + half*64;
        #pragma unroll
        for(int it=0; it<8; ++it){
            float f[8]; cvt8(((const int4*)src)[it], f);
            float4 lo; lo.x=f[0]; lo.y=f[1]; lo.z=f[2]; lo.w=f[3];
            float4 hi; hi.x=f[4]; hi.y=f[5]; hi.z=f[6]; hi.w=f[7];
            ((float4*)dst)[it*2  ] = lo;
            ((float4*)dst)[it*2+1] = hi;
        }
    }
}

// ---------------- launch ----------------
extern "C" void kernel_launch(void* const* d_in, const int* in_sizes, int n_in,
                              void* d_out, int out_size, void* d_ws, size_t ws_size,
                              hipStream_t stream){
    const float* z    = (const float*)d_in[0];
    const int*   mask = (const int*)d_in[1];

    char* ws = (char*)d_ws;
    const size_t MB = (size_t)1<<20;
    u16* zn   = (u16*)(ws + 0*MB);      // 16 MB [t][128] bf16
    u16* attn = (u16*)(ws + 16*MB);     // 16 MB [t][128] bf16
    u16* pb   = (u16*)(ws + 32*MB);     // ~231 KB bf16 param block (incl. combined weights)

    prep_params<<<NCONV+129,256,0,stream>>>(
        (const float*)d_in[2],  (const float*)d_in[3],  (const float*)d_in[4],  (const float*)d_in[5],
        (const float*)d_in[6],  (const float*)d_in[7],  (const float*)d_in[8],  (const float*)d_in[9],
        (const float*)d_in[10], (const float*)d_in[11], (const float*)d_in[12], (const float*)d_in[13],
        (const float*)d_in[14], (const float*)d_in[15], (const float*)d_in[16], (const float*)d_in[17],
        pb);
    ln_kernel<<<16384,256,0,stream>>>(z, pb, zn);
    mega_kernel<<<1024,256,0,stream>>>(zn, mask, pb, attn);
    oproj_kernel<<<512,256,0,stream>>>(attn, pb, mask, (float*)d_out);
}